// Round 1
// baseline (448.411 us; speedup 1.0000x reference)
//
#include <hip/hip_runtime.h>

// MultiHeadAttention: B=2,S=2048,D=1024,H=16,Dh=64, fp32 in/out.
// K1: QKV projection (split-bf16 MFMA, fp32-accurate). Q pre-scaled 1/8.
//     Q,K -> ws fp32 [4096][1024]; V -> ws bf16 TRANSPOSED [1024][4096].
// K2: per (b,h,q-block128): passA row-sums L, passB attn write + PV.
// ws usage: 16MB (Q) + 16MB (K) + 8MB (Vt) = 40MB.

typedef __attribute__((ext_vector_type(8))) short bf16x8;
typedef __attribute__((ext_vector_type(4))) float f32x4;

#define MFMA16(a, b, c) __builtin_amdgcn_mfma_f32_16x16x32_bf16((a), (b), (c), 0, 0, 0)

static __device__ __forceinline__ unsigned short f2bf(float x) {
    unsigned int u = __builtin_bit_cast(unsigned int, x);
    u += 0x7fffu + ((u >> 16) & 1u);           // round-to-nearest-even
    return (unsigned short)(u >> 16);
}
static __device__ __forceinline__ float bf2f(unsigned short s) {
    return __builtin_bit_cast(float, ((unsigned int)s) << 16);
}
// split fp32 -> bf16 hi + bf16 lo (x ~= hi + lo to ~2^-17 rel)
static __device__ __forceinline__ void split8(float4 f0, float4 f1, bf16x8& vh, bf16x8& vl) {
    float a; unsigned short hb;
    a = f0.x; hb = f2bf(a); vh[0] = (short)hb; vl[0] = (short)f2bf(a - bf2f(hb));
    a = f0.y; hb = f2bf(a); vh[1] = (short)hb; vl[1] = (short)f2bf(a - bf2f(hb));
    a = f0.z; hb = f2bf(a); vh[2] = (short)hb; vl[2] = (short)f2bf(a - bf2f(hb));
    a = f0.w; hb = f2bf(a); vh[3] = (short)hb; vl[3] = (short)f2bf(a - bf2f(hb));
    a = f1.x; hb = f2bf(a); vh[4] = (short)hb; vl[4] = (short)f2bf(a - bf2f(hb));
    a = f1.y; hb = f2bf(a); vh[5] = (short)hb; vl[5] = (short)f2bf(a - bf2f(hb));
    a = f1.z; hb = f2bf(a); vh[6] = (short)hb; vl[6] = (short)f2bf(a - bf2f(hb));
    a = f1.w; hb = f2bf(a); vh[7] = (short)hb; vl[7] = (short)f2bf(a - bf2f(hb));
}

// ---------------- K1: QKV projection GEMM  C[m,n] = sum_k X[m,k]*W[n,k] + b[n]
__global__ __launch_bounds__(256, 2) void qkv_proj(
    const float* __restrict__ query, const float* __restrict__ key_, const float* __restrict__ value,
    const float* __restrict__ Wq, const float* __restrict__ bq,
    const float* __restrict__ Wk, const float* __restrict__ bk,
    const float* __restrict__ Wv, const float* __restrict__ bv,
    float* __restrict__ q_ws, float* __restrict__ k_ws, unsigned short* __restrict__ vt_ws)
{
    __shared__ unsigned short sAh[128 * 40];   // +8 pad: conflict-free b128 frag reads
    __shared__ unsigned short sAl[128 * 40];
    __shared__ unsigned short sBh[128 * 40];
    __shared__ unsigned short sBl[128 * 40];

    const int z = blockIdx.z;
    const float* __restrict__ X    = (z == 0) ? query : (z == 1) ? key_ : value;
    const float* __restrict__ W    = (z == 0) ? Wq    : (z == 1) ? Wk   : Wv;
    const float* __restrict__ bias = (z == 0) ? bq    : (z == 1) ? bk   : bv;

    const int t = threadIdx.x;
    const int l = t & 63;
    const int w = t >> 6;
    const int lr = l & 15;
    const int lk = (l >> 4) * 8;
    const int m0 = blockIdx.y * 128;
    const int n0 = blockIdx.x * 128;
    const int wr = (w >> 1) * 64;
    const int wc = (w & 1) * 64;
    const int srow = t >> 1;            // staging: 2 threads per 128-row, 16 floats each
    const int sc0 = (t & 1) * 16;

    f32x4 acc[4][4];
#pragma unroll
    for (int i = 0; i < 4; i++)
#pragma unroll
        for (int j = 0; j < 4; j++) acc[i][j] = (f32x4){0.f, 0.f, 0.f, 0.f};

    for (int kk = 0; kk < 1024; kk += 32) {
        __syncthreads();
#pragma unroll
        for (int u = 0; u < 4; u++) {
            float4 fa = *(const float4*)(&X[(size_t)(m0 + srow) * 1024 + kk + sc0 + 4 * u]);
            float4 fb = *(const float4*)(&W[(size_t)(n0 + srow) * 1024 + kk + sc0 + 4 * u]);
            ushort4 ah, al, bh, bl;
            ah.x = f2bf(fa.x); al.x = f2bf(fa.x - bf2f(ah.x));
            ah.y = f2bf(fa.y); al.y = f2bf(fa.y - bf2f(ah.y));
            ah.z = f2bf(fa.z); al.z = f2bf(fa.z - bf2f(ah.z));
            ah.w = f2bf(fa.w); al.w = f2bf(fa.w - bf2f(ah.w));
            bh.x = f2bf(fb.x); bl.x = f2bf(fb.x - bf2f(bh.x));
            bh.y = f2bf(fb.y); bl.y = f2bf(fb.y - bf2f(bh.y));
            bh.z = f2bf(fb.z); bl.z = f2bf(fb.z - bf2f(bh.z));
            bh.w = f2bf(fb.w); bl.w = f2bf(fb.w - bf2f(bh.w));
            const int si = srow * 40 + sc0 + 4 * u;
            *(ushort4*)(&sAh[si]) = ah;
            *(ushort4*)(&sAl[si]) = al;
            *(ushort4*)(&sBh[si]) = bh;
            *(ushort4*)(&sBl[si]) = bl;
        }
        __syncthreads();
        bf16x8 Ah[4], Al[4], Bh[4], Bl[4];
#pragma unroll
        for (int i = 0; i < 4; i++) {
            Ah[i] = *(const bf16x8*)(&sAh[(wr + i * 16 + lr) * 40 + lk]);
            Al[i] = *(const bf16x8*)(&sAl[(wr + i * 16 + lr) * 40 + lk]);
            Bh[i] = *(const bf16x8*)(&sBh[(wc + i * 16 + lr) * 40 + lk]);
            Bl[i] = *(const bf16x8*)(&sBl[(wc + i * 16 + lr) * 40 + lk]);
        }
#pragma unroll
        for (int i = 0; i < 4; i++)
#pragma unroll
            for (int j = 0; j < 4; j++) {
                acc[i][j] = MFMA16(Ah[i], Bh[j], acc[i][j]);
                acc[i][j] = MFMA16(Ah[i], Bl[j], acc[i][j]);
                acc[i][j] = MFMA16(Al[i], Bh[j], acc[i][j]);
            }
    }

    // epilogue: C/D layout col=lane&15, row=(lane>>4)*4+r
#pragma unroll
    for (int i = 0; i < 4; i++)
#pragma unroll
        for (int j = 0; j < 4; j++) {
            const int gcol = n0 + wc + j * 16 + lr;
            const float bb = bias[gcol];
            const int grow0 = m0 + wr + i * 16 + (l >> 4) * 4;
            if (z == 2) {  // V: bf16, transposed [1024][4096]
                ushort4 pk;
                pk.x = f2bf(acc[i][j][0] + bb);
                pk.y = f2bf(acc[i][j][1] + bb);
                pk.z = f2bf(acc[i][j][2] + bb);
                pk.w = f2bf(acc[i][j][3] + bb);
                *(ushort4*)(&vt_ws[(size_t)gcol * 4096 + grow0]) = pk;
            } else {
                float* dst = (z == 0) ? q_ws : k_ws;
                const float s = (z == 0) ? 0.125f : 1.0f;  // fold 1/sqrt(Dh) into Q
#pragma unroll
                for (int r = 0; r < 4; r++)
                    dst[(size_t)(grow0 + r) * 1024 + gcol] = (acc[i][j][r] + bb) * s;
            }
        }
}

// stage K-tile [128 k-rows][64 d] fp32 -> hi/lo bf16, XOR-swizzled
static __device__ __forceinline__ void stage_K(
    const float* __restrict__ k_ws, unsigned short* sKh, unsigned short* sKl,
    int b, int h, int k0, int t)
{
    const int row = t >> 1;
    const int c0 = (t & 1) * 32;
    const float* src = &k_ws[(size_t)(b * 2048 + k0 + row) * 1024 + h * 64 + c0];
#pragma unroll
    for (int u = 0; u < 8; u++) {
        float4 f = *(const float4*)(src + 4 * u);
        ushort4 hh, ll;
        hh.x = f2bf(f.x); ll.x = f2bf(f.x - bf2f(hh.x));
        hh.y = f2bf(f.y); ll.y = f2bf(f.y - bf2f(hh.y));
        hh.z = f2bf(f.z); ll.z = f2bf(f.z - bf2f(hh.z));
        hh.w = f2bf(f.w); ll.w = f2bf(f.w - bf2f(hh.w));
        const int idx = (row * 64 + c0 + 4 * u) ^ ((row & 7) << 3);
        *(ushort4*)(&sKh[idx]) = hh;
        *(ushort4*)(&sKl[idx]) = ll;
    }
}

static __device__ __forceinline__ void compute_scores(
    const unsigned short* sKh, const unsigned short* sKl,
    const bf16x8 (&qh)[2][2], const bf16x8 (&ql)[2][2],
    int lr, int lg, f32x4 (&sc)[2][8])
{
#pragma unroll
    for (int m = 0; m < 2; m++)
#pragma unroll
        for (int n = 0; n < 8; n++) sc[m][n] = (f32x4){0.f, 0.f, 0.f, 0.f};
#pragma unroll
    for (int n = 0; n < 8; n++) {
        const int row = n * 16 + lr;
#pragma unroll
        for (int kc = 0; kc < 2; kc++) {
            const int idx = (row * 64 + kc * 32 + lg * 8) ^ ((row & 7) << 3);
            const bf16x8 Bh = *(const bf16x8*)(&sKh[idx]);
            const bf16x8 Bl = *(const bf16x8*)(&sKl[idx]);
#pragma unroll
            for (int m = 0; m < 2; m++) {
                sc[m][n] = MFMA16(qh[m][kc], Bh, sc[m][n]);
                sc[m][n] = MFMA16(qh[m][kc], Bl, sc[m][n]);
                sc[m][n] = MFMA16(ql[m][kc], Bh, sc[m][n]);
            }
        }
    }
}

// ---------------- K2: fused attention per (b, h, q-block of 128)
__global__ __launch_bounds__(256, 2) void attn_fused(
    const float* __restrict__ q_ws, const float* __restrict__ k_ws,
    const unsigned short* __restrict__ vt_ws,
    float* __restrict__ ctx_out, float* __restrict__ attn_out)
{
    __shared__ unsigned short sKh[128 * 64];   // 16KB
    __shared__ unsigned short sKl[128 * 64];   // 16KB
    __shared__ unsigned short sVT[64 * 128];   // 16KB  V^T tile [d][k]
    __shared__ unsigned short sP [128 * 128];  // 32KB  P' tile, per-wave-private rows

    const int t = threadIdx.x;
    const int l = t & 63;
    const int w = t >> 6;
    const int lr = l & 15;
    const int lg = l >> 4;
    const int qb = blockIdx.x;
    const int h  = blockIdx.y;
    const int b  = blockIdx.z;
    const int sq0 = qb * 128 + w * 32;   // this wave's 32 q-rows

    // Q fragments (hi/lo), direct from global (one-time)
    bf16x8 qh[2][2], ql[2][2];
#pragma unroll
    for (int m = 0; m < 2; m++) {
        const int grow = b * 2048 + sq0 + m * 16 + lr;
#pragma unroll
        for (int kc = 0; kc < 2; kc++) {
            const float* src = &q_ws[(size_t)grow * 1024 + h * 64 + kc * 32 + lg * 8];
            float4 f0 = *(const float4*)(src);
            float4 f1 = *(const float4*)(src + 4);
            split8(f0, f1, qh[m][kc], ql[m][kc]);
        }
    }

    // ---- pass A: row sums L = sum_k exp(s)
    float Ls[2][4];
#pragma unroll
    for (int m = 0; m < 2; m++)
#pragma unroll
        for (int r = 0; r < 4; r++) Ls[m][r] = 0.f;

    for (int kt = 0; kt < 16; kt++) {
        __syncthreads();
        stage_K(k_ws, sKh, sKl, b, h, kt * 128, t);
        __syncthreads();
        f32x4 sc[2][8];
        compute_scores(sKh, sKl, qh, ql, lr, lg, sc);
#pragma unroll
        for (int m = 0; m < 2; m++)
#pragma unroll
            for (int r = 0; r < 4; r++) {
                float v = __expf(sc[m][0][r]) + __expf(sc[m][1][r]) + __expf(sc[m][2][r]) +
                          __expf(sc[m][3][r]) + __expf(sc[m][4][r]) + __expf(sc[m][5][r]) +
                          __expf(sc[m][6][r]) + __expf(sc[m][7][r]);
                v += __shfl_xor(v, 1);
                v += __shfl_xor(v, 2);
                v += __shfl_xor(v, 4);
                v += __shfl_xor(v, 8);
                Ls[m][r] += v;
            }
    }

    float invL[2][4];
#pragma unroll
    for (int m = 0; m < 2; m++)
#pragma unroll
        for (int r = 0; r < 4; r++) invL[m][r] = 1.0f / Ls[m][r];

    // ---- pass B: write attn + accumulate PV
    f32x4 pv[2][4];
#pragma unroll
    for (int m = 0; m < 2; m++)
#pragma unroll
        for (int n = 0; n < 4; n++) pv[m][n] = (f32x4){0.f, 0.f, 0.f, 0.f};

    for (int kt = 0; kt < 16; kt++) {
        const int k0 = kt * 128;
        __syncthreads();
        stage_K(k_ws, sKh, sKl, b, h, k0, t);
        {   // stage V^T tile [64 d][128 k] bf16 (already transposed in ws)
            const int vd = t >> 2;
            const int vq0 = (t & 3) * 32;
            const unsigned short* vsrc = &vt_ws[(size_t)(h * 64 + vd) * 4096 + b * 2048 + k0 + vq0];
#pragma unroll
            for (int u = 0; u < 4; u++) {
                uint4 val = *(const uint4*)(vsrc + 8 * u);
                const int idx = (vd * 128 + vq0 + 8 * u) ^ ((vd & 7) << 3);
                *(uint4*)(&sVT[idx]) = val;
            }
        }
        __syncthreads();
        f32x4 sc[2][8];
        compute_scores(sKh, sKl, qh, ql, lr, lg, sc);

        // exp -> attn write (fp32, normalized) + P' bf16 to LDS (per-wave rows)
#pragma unroll
        for (int m = 0; m < 2; m++)
#pragma unroll
            for (int r = 0; r < 4; r++) {
                const int sq = sq0 + m * 16 + lg * 4 + r;
                const size_t abase = (((size_t)(h * 2 + b)) * 2048 + sq) * 2048 + k0;
                const int prow = w * 32 + m * 16 + lg * 4 + r;
                const float il = invL[m][r];
#pragma unroll
                for (int n = 0; n < 8; n++) {
                    const float p = __expf(sc[m][n][r]);
                    const int colk = n * 16 + lr;
                    sP[(prow * 128 + colk) ^ ((prow & 7) << 3)] = f2bf(p);
                    attn_out[abase + colk] = p * il;
                }
            }

        // PV: ctx += P' @ V  (K-dim = 128 of this tile)
#pragma unroll
        for (int kc = 0; kc < 4; kc++) {
            bf16x8 pa[2];
#pragma unroll
            for (int m = 0; m < 2; m++) {
                const int prow = w * 32 + m * 16 + lr;
                pa[m] = *(const bf16x8*)(&sP[(prow * 128 + kc * 32 + lg * 8) ^ ((prow & 7) << 3)]);
            }
#pragma unroll
            for (int n = 0; n < 4; n++) {
                const int vrow = n * 16 + lr;
                const bf16x8 vb = *(const bf16x8*)(&sVT[(vrow * 128 + kc * 32 + lg * 8) ^ ((vrow & 7) << 3)]);
#pragma unroll
                for (int m = 0; m < 2; m++) pv[m][n] = MFMA16(pa[m], vb, pv[m][n]);
            }
        }
    }

    // epilogue: context = (P' @ V) / L
#pragma unroll
    for (int m = 0; m < 2; m++)
#pragma unroll
        for (int r = 0; r < 4; r++) {
            const int sq = sq0 + m * 16 + lg * 4 + r;
            const float il = invL[m][r];
#pragma unroll
            for (int n = 0; n < 4; n++)
                ctx_out[((size_t)(b * 2048 + sq)) * 1024 + h * 64 + n * 16 + lr] =
                    pv[m][n][r] * il;
        }
}

extern "C" void kernel_launch(void* const* d_in, const int* in_sizes, int n_in,
                              void* d_out, int out_size, void* d_ws, size_t ws_size,
                              hipStream_t stream)
{
    const float* query = (const float*)d_in[0];
    const float* key_  = (const float*)d_in[1];
    const float* value = (const float*)d_in[2];
    const float* Wq = (const float*)d_in[3];
    const float* bq = (const float*)d_in[4];
    const float* Wk = (const float*)d_in[5];
    const float* bk = (const float*)d_in[6];
    const float* Wv = (const float*)d_in[7];
    const float* bv = (const float*)d_in[8];

    float* q_ws = (float*)d_ws;                                   // 16 MB
    float* k_ws = q_ws + (size_t)4096 * 1024;                     // 16 MB
    unsigned short* vt_ws = (unsigned short*)(k_ws + (size_t)4096 * 1024); // 8 MB, V^T

    float* ctx_out  = (float*)d_out;
    float* attn_out = ctx_out + (size_t)2 * 2048 * 1024;

    dim3 g1(8, 32, 3);
    qkv_proj<<<g1, 256, 0, stream>>>(query, key_, value, Wq, bq, Wk, bk, Wv, bv,
                                     q_ws, k_ws, vt_ws);
    dim3 g2(16, 16, 2);
    attn_fused<<<g2, 256, 0, stream>>>(q_ws, k_ws, vt_ws, ctx_out, attn_out);
}

// Round 2
// 409.764 us; speedup vs baseline: 1.0943x; 1.0943x over previous
//
#include <hip/hip_runtime.h>

// MultiHeadAttention: B=2,S=2048,D=1024,H=16,Dh=64, fp32 in/out.
// K1: QKV projection (split-bf16 MFMA, fp32-accurate).
//     Q -> ws fp32 [4096][1024] (pre-scaled 1/8); K -> ws bf16 [4096][1024];
//     V -> ws bf16 TRANSPOSED [1024][4096].
// K2: per (b,h,q-block128), XCD-swizzled: passA row-sums L (q_hi-only scores),
//     passB attn write (vectorized via P-LDS readback) + PV.
// ws: 16MB (Q fp32) + 8MB (K bf16) + 8MB (Vt bf16) = 32MB.

typedef __attribute__((ext_vector_type(8))) short bf16x8;
typedef __attribute__((ext_vector_type(4))) float f32x4;

#define MFMA16(a, b, c) __builtin_amdgcn_mfma_f32_16x16x32_bf16((a), (b), (c), 0, 0, 0)

static __device__ __forceinline__ unsigned short f2bf(float x) {
    unsigned int u = __builtin_bit_cast(unsigned int, x);
    u += 0x7fffu + ((u >> 16) & 1u);           // round-to-nearest-even
    return (unsigned short)(u >> 16);
}
static __device__ __forceinline__ float bf2f(unsigned short s) {
    return __builtin_bit_cast(float, ((unsigned int)s) << 16);
}
// split fp32 -> bf16 hi + bf16 lo (x ~= hi + lo to ~2^-17 rel)
static __device__ __forceinline__ void split8(float4 f0, float4 f1, bf16x8& vh, bf16x8& vl) {
    float a; unsigned short hb;
    a = f0.x; hb = f2bf(a); vh[0] = (short)hb; vl[0] = (short)f2bf(a - bf2f(hb));
    a = f0.y; hb = f2bf(a); vh[1] = (short)hb; vl[1] = (short)f2bf(a - bf2f(hb));
    a = f0.z; hb = f2bf(a); vh[2] = (short)hb; vl[2] = (short)f2bf(a - bf2f(hb));
    a = f0.w; hb = f2bf(a); vh[3] = (short)hb; vl[3] = (short)f2bf(a - bf2f(hb));
    a = f1.x; hb = f2bf(a); vh[4] = (short)hb; vl[4] = (short)f2bf(a - bf2f(hb));
    a = f1.y; hb = f2bf(a); vh[5] = (short)hb; vl[5] = (short)f2bf(a - bf2f(hb));
    a = f1.z; hb = f2bf(a); vh[6] = (short)hb; vl[6] = (short)f2bf(a - bf2f(hb));
    a = f1.w; hb = f2bf(a); vh[7] = (short)hb; vl[7] = (short)f2bf(a - bf2f(hb));
}

// async global(bf16,16B) -> LDS, dest = wave-uniform base + lane*16
static __device__ __forceinline__ void gload16(const unsigned short* g, unsigned short* l) {
    __builtin_amdgcn_global_load_lds(
        (const __attribute__((address_space(1))) unsigned int*)g,
        (__attribute__((address_space(3))) unsigned int*)l, 16, 0, 0);
}

// ---------------- K1: QKV projection GEMM  C[m,n] = sum_k X[m,k]*W[n,k] + b[n]
__global__ __launch_bounds__(256, 2) void qkv_proj(
    const float* __restrict__ query, const float* __restrict__ key_, const float* __restrict__ value,
    const float* __restrict__ Wq, const float* __restrict__ bq,
    const float* __restrict__ Wk, const float* __restrict__ bk,
    const float* __restrict__ Wv, const float* __restrict__ bv,
    float* __restrict__ q_ws, unsigned short* __restrict__ kb_ws, unsigned short* __restrict__ vt_ws)
{
    __shared__ unsigned short sAh[128 * 40];   // +8 pad: conflict-free b128 frag reads
    __shared__ unsigned short sAl[128 * 40];
    __shared__ unsigned short sBh[128 * 40];
    __shared__ unsigned short sBl[128 * 40];

    const int z = blockIdx.z;
    const float* __restrict__ X    = (z == 0) ? query : (z == 1) ? key_ : value;
    const float* __restrict__ W    = (z == 0) ? Wq    : (z == 1) ? Wk   : Wv;
    const float* __restrict__ bias = (z == 0) ? bq    : (z == 1) ? bk   : bv;

    const int t = threadIdx.x;
    const int l = t & 63;
    const int w = t >> 6;
    const int lr = l & 15;
    const int lk = (l >> 4) * 8;
    const int m0 = blockIdx.y * 128;
    const int n0 = blockIdx.x * 128;
    const int wr = (w >> 1) * 64;
    const int wc = (w & 1) * 64;
    const int srow = t >> 1;            // staging: 2 threads per 128-row, 16 floats each
    const int sc0 = (t & 1) * 16;

    f32x4 acc[4][4];
#pragma unroll
    for (int i = 0; i < 4; i++)
#pragma unroll
        for (int j = 0; j < 4; j++) acc[i][j] = (f32x4){0.f, 0.f, 0.f, 0.f};

    for (int kk = 0; kk < 1024; kk += 32) {
        __syncthreads();
#pragma unroll
        for (int u = 0; u < 4; u++) {
            float4 fa = *(const float4*)(&X[(size_t)(m0 + srow) * 1024 + kk + sc0 + 4 * u]);
            float4 fb = *(const float4*)(&W[(size_t)(n0 + srow) * 1024 + kk + sc0 + 4 * u]);
            ushort4 ah, al, bh, bl;
            ah.x = f2bf(fa.x); al.x = f2bf(fa.x - bf2f(ah.x));
            ah.y = f2bf(fa.y); al.y = f2bf(fa.y - bf2f(ah.y));
            ah.z = f2bf(fa.z); al.z = f2bf(fa.z - bf2f(ah.z));
            ah.w = f2bf(fa.w); al.w = f2bf(fa.w - bf2f(ah.w));
            bh.x = f2bf(fb.x); bl.x = f2bf(fb.x - bf2f(bh.x));
            bh.y = f2bf(fb.y); bl.y = f2bf(fb.y - bf2f(bh.y));
            bh.z = f2bf(fb.z); bl.z = f2bf(fb.z - bf2f(bh.z));
            bh.w = f2bf(fb.w); bl.w = f2bf(fb.w - bf2f(bh.w));
            const int si = srow * 40 + sc0 + 4 * u;
            *(ushort4*)(&sAh[si]) = ah;
            *(ushort4*)(&sAl[si]) = al;
            *(ushort4*)(&sBh[si]) = bh;
            *(ushort4*)(&sBl[si]) = bl;
        }
        __syncthreads();
        bf16x8 Ah[4], Al[4], Bh[4], Bl[4];
#pragma unroll
        for (int i = 0; i < 4; i++) {
            Ah[i] = *(const bf16x8*)(&sAh[(wr + i * 16 + lr) * 40 + lk]);
            Al[i] = *(const bf16x8*)(&sAl[(wr + i * 16 + lr) * 40 + lk]);
            Bh[i] = *(const bf16x8*)(&sBh[(wc + i * 16 + lr) * 40 + lk]);
            Bl[i] = *(const bf16x8*)(&sBl[(wc + i * 16 + lr) * 40 + lk]);
        }
        __builtin_amdgcn_s_setprio(1);
#pragma unroll
        for (int i = 0; i < 4; i++)
#pragma unroll
            for (int j = 0; j < 4; j++) {
                acc[i][j] = MFMA16(Ah[i], Bh[j], acc[i][j]);
                acc[i][j] = MFMA16(Ah[i], Bl[j], acc[i][j]);
                acc[i][j] = MFMA16(Al[i], Bh[j], acc[i][j]);
            }
        __builtin_amdgcn_s_setprio(0);
    }

    // epilogue: C/D layout col=lane&15, row=(lane>>4)*4+r
#pragma unroll
    for (int i = 0; i < 4; i++)
#pragma unroll
        for (int j = 0; j < 4; j++) {
            const int gcol = n0 + wc + j * 16 + lr;
            const float bb = bias[gcol];
            const int grow0 = m0 + wr + i * 16 + (l >> 4) * 4;
            if (z == 2) {  // V: bf16, transposed [1024][4096]
                ushort4 pk;
                pk.x = f2bf(acc[i][j][0] + bb);
                pk.y = f2bf(acc[i][j][1] + bb);
                pk.z = f2bf(acc[i][j][2] + bb);
                pk.w = f2bf(acc[i][j][3] + bb);
                *(ushort4*)(&vt_ws[(size_t)gcol * 4096 + grow0]) = pk;
            } else if (z == 1) {  // K: bf16 row-major
#pragma unroll
                for (int r = 0; r < 4; r++)
                    kb_ws[(size_t)(grow0 + r) * 1024 + gcol] = f2bf(acc[i][j][r] + bb);
            } else {             // Q: fp32, 1/sqrt(Dh) folded in
#pragma unroll
                for (int r = 0; r < 4; r++)
                    q_ws[(size_t)(grow0 + r) * 1024 + gcol] = (acc[i][j][r] + bb) * 0.125f;
            }
        }
}

// QK^T scores: A = Q frag (hi [, lo]), B = K rows from swizzled LDS
template<int TERMS>
static __device__ __forceinline__ void compute_scores(
    const unsigned short* sKh,
    const bf16x8 (&qh)[2][2], const bf16x8 (&ql)[2][2],
    int lr, int lg, f32x4 (&sc)[2][8])
{
#pragma unroll
    for (int m = 0; m < 2; m++)
#pragma unroll
        for (int n = 0; n < 8; n++) sc[m][n] = (f32x4){0.f, 0.f, 0.f, 0.f};
    __builtin_amdgcn_s_setprio(1);
#pragma unroll
    for (int n = 0; n < 8; n++) {
        const int row = n * 16 + lr;
#pragma unroll
        for (int kc = 0; kc < 2; kc++) {
            const int idx = (row * 64 + kc * 32 + lg * 8) ^ ((row & 7) << 3);
            const bf16x8 Bh = *(const bf16x8*)(&sKh[idx]);
#pragma unroll
            for (int m = 0; m < 2; m++) {
                sc[m][n] = MFMA16(qh[m][kc], Bh, sc[m][n]);
                if (TERMS == 2) sc[m][n] = MFMA16(ql[m][kc], Bh, sc[m][n]);
            }
        }
    }
    __builtin_amdgcn_s_setprio(0);
}

// ---------------- K2: fused attention per (b, h, q-block of 128)
__global__ __launch_bounds__(256, 3) void attn_fused(
    const float* __restrict__ q_ws, const unsigned short* __restrict__ kb_ws,
    const unsigned short* __restrict__ vt_ws,
    float* __restrict__ ctx_out, float* __restrict__ attn_out)
{
    __shared__ unsigned short sKh[128 * 64];   // 16KB K tile (bf16, XOR-swizzled)
    __shared__ unsigned short sVT[64 * 128];   // 16KB V^T tile [d][k]
    __shared__ unsigned short sP [128 * 64];   // 16KB P' half-tile, per-wave rows
    __shared__ float sInvL[128];

    const int t = threadIdx.x;
    const int l = t & 63;
    const int w = t >> 6;
    const int lr = l & 15;
    const int lg = l >> 4;
    // XCD swizzle: 512 blocks = 8 XCDs x 64; chunk shares 4 (b,h) K/V panels (2MB, L2-fit)
    const int o  = (blockIdx.x & 7) * 64 + (blockIdx.x >> 3);
    const int qb = o & 15;
    const int h  = (o >> 4) & 15;
    const int b  = o >> 8;
    const int sq0 = qb * 128 + w * 32;   // this wave's 32 q-rows

    // Q fragments (hi/lo), fp32 source, one-time
    bf16x8 qh[2][2], ql[2][2];
#pragma unroll
    for (int m = 0; m < 2; m++) {
        const int grow = b * 2048 + sq0 + m * 16 + lr;
#pragma unroll
        for (int kc = 0; kc < 2; kc++) {
            const float* src = &q_ws[(size_t)grow * 1024 + h * 64 + kc * 32 + lg * 8];
            float4 f0 = *(const float4*)(src);
            float4 f1 = *(const float4*)(src + 4);
            split8(f0, f1, qh[m][kc], ql[m][kc]);
        }
    }

    // ---- pass A: row sums L = sum_k exp(s)  (q_hi-only scores: L rel-err ~1e-4)
    float Ls[2][4];
#pragma unroll
    for (int m = 0; m < 2; m++)
#pragma unroll
        for (int r = 0; r < 4; r++) Ls[m][r] = 0.f;

    for (int kt = 0; kt < 16; kt++) {
        __syncthreads();
#pragma unroll
        for (int u = 0; u < 4; u++) {   // async K stage: wave-own quarter, swizzled src
            const int row = w * 32 + u * 8 + (l >> 3);
            const int col = ((l & 7) * 8) ^ ((row & 7) << 3);
            gload16(&kb_ws[(size_t)(b * 2048 + kt * 128 + row) * 1024 + h * 64 + col],
                    &sKh[w * 2048 + u * 512]);
        }
        __syncthreads();
        f32x4 sc[2][8];
        compute_scores<1>(sKh, qh, ql, lr, lg, sc);
#pragma unroll
        for (int m = 0; m < 2; m++)
#pragma unroll
            for (int r = 0; r < 4; r++) {
                float v = __expf(sc[m][0][r]) + __expf(sc[m][1][r]) + __expf(sc[m][2][r]) +
                          __expf(sc[m][3][r]) + __expf(sc[m][4][r]) + __expf(sc[m][5][r]) +
                          __expf(sc[m][6][r]) + __expf(sc[m][7][r]);
                v += __shfl_xor(v, 1);
                v += __shfl_xor(v, 2);
                v += __shfl_xor(v, 4);
                v += __shfl_xor(v, 8);
                Ls[m][r] += v;
            }
    }

    float invL[2][4];
#pragma unroll
    for (int m = 0; m < 2; m++)
#pragma unroll
        for (int r = 0; r < 4; r++) {
            invL[m][r] = 1.0f / Ls[m][r];
            if (lr == 0) sInvL[w * 32 + m * 16 + lg * 4 + r] = invL[m][r];
        }

    // ---- pass B: attn write + PV accumulate
    f32x4 pv[2][4];
#pragma unroll
    for (int m = 0; m < 2; m++)
#pragma unroll
        for (int n = 0; n < 4; n++) pv[m][n] = (f32x4){0.f, 0.f, 0.f, 0.f};

    for (int kt = 0; kt < 16; kt++) {
        const int k0 = kt * 128;
        __syncthreads();
#pragma unroll
        for (int u = 0; u < 4; u++) {   // K stage
            const int row = w * 32 + u * 8 + (l >> 3);
            const int col = ((l & 7) * 8) ^ ((row & 7) << 3);
            gload16(&kb_ws[(size_t)(b * 2048 + k0 + row) * 1024 + h * 64 + col],
                    &sKh[w * 2048 + u * 512]);
        }
#pragma unroll
        for (int u = 0; u < 4; u++) {   // V^T stage
            const int d = w * 16 + u * 4 + (l >> 4);
            const int kk = ((l & 15) * 8) ^ ((d & 7) << 3);
            gload16(&vt_ws[(size_t)(h * 64 + d) * 4096 + b * 2048 + k0 + kk],
                    &sVT[w * 2048 + u * 512]);
        }
        __syncthreads();
        f32x4 sc[2][8];
        compute_scores<2>(sKh, qh, ql, lr, lg, sc);

#pragma unroll
        for (int c = 0; c < 2; c++) {   // two 64-col halves through sP
            // exp -> P' bf16 into wave-private sP rows
#pragma unroll
            for (int m = 0; m < 2; m++)
#pragma unroll
                for (int r = 0; r < 4; r++) {
                    const int prow = w * 32 + m * 16 + lg * 4 + r;
#pragma unroll
                    for (int nn = 0; nn < 4; nn++) {
                        const float p = __expf(sc[m][c * 4 + nn][r]);
                        sP[(prow * 64 + nn * 16 + lr) ^ ((prow & 7) << 3)] = f2bf(p);
                    }
                }
            // attn store: vectorized readback, float4 per lane
#pragma unroll
            for (int i = 0; i < 8; i++) {
                const int prow = w * 32 + lg * 8 + i;
                const float il = sInvL[prow];
                ushort4 pk = *(const ushort4*)(&sP[(prow * 64 + lr * 4) ^ ((prow & 7) << 3)]);
                float4 oo;
                oo.x = bf2f(pk.x) * il;
                oo.y = bf2f(pk.y) * il;
                oo.z = bf2f(pk.z) * il;
                oo.w = bf2f(pk.w) * il;
                const size_t arow = (size_t)(h * 2 + b) * 2048 + qb * 128 + prow;
                *(float4*)(&attn_out[arow * 2048 + k0 + c * 64 + lr * 4]) = oo;
            }
            // PV: ctx += P' @ V over this 64-k half
            __builtin_amdgcn_s_setprio(1);
#pragma unroll
            for (int kcl = 0; kcl < 2; kcl++) {
                bf16x8 pa[2];
#pragma unroll
                for (int m = 0; m < 2; m++) {
                    const int prow = w * 32 + m * 16 + lr;
                    pa[m] = *(const bf16x8*)(&sP[(prow * 64 + kcl * 32 + lg * 8) ^ ((prow & 7) << 3)]);
                }
#pragma unroll
                for (int n = 0; n < 4; n++) {
                    const int vrow = n * 16 + lr;
                    const bf16x8 vb = *(const bf16x8*)(&sVT[(vrow * 128 + c * 64 + kcl * 32 + lg * 8) ^ ((vrow & 7) << 3)]);
#pragma unroll
                    for (int m = 0; m < 2; m++) pv[m][n] = MFMA16(pa[m], vb, pv[m][n]);
                }
            }
            __builtin_amdgcn_s_setprio(0);
        }
    }

    // epilogue: context = (P' @ V) / L
#pragma unroll
    for (int m = 0; m < 2; m++)
#pragma unroll
        for (int r = 0; r < 4; r++) {
            const int sq = sq0 + m * 16 + lg * 4 + r;
            const float il = invL[m][r];
#pragma unroll
            for (int n = 0; n < 4; n++)
                ctx_out[((size_t)(b * 2048 + sq)) * 1024 + h * 64 + n * 16 + lr] =
                    pv[m][n][r] * il;
        }
}

extern "C" void kernel_launch(void* const* d_in, const int* in_sizes, int n_in,
                              void* d_out, int out_size, void* d_ws, size_t ws_size,
                              hipStream_t stream)
{
    const float* query = (const float*)d_in[0];
    const float* key_  = (const float*)d_in[1];
    const float* value = (const float*)d_in[2];
    const float* Wq = (const float*)d_in[3];
    const float* bq = (const float*)d_in[4];
    const float* Wk = (const float*)d_in[5];
    const float* bk = (const float*)d_in[6];
    const float* Wv = (const float*)d_in[7];
    const float* bv = (const float*)d_in[8];

    float* q_ws = (float*)d_ws;                                        // 16 MB fp32
    unsigned short* kb_ws = (unsigned short*)(q_ws + (size_t)4096 * 1024);  // 8 MB bf16
    unsigned short* vt_ws = kb_ws + (size_t)4096 * 1024;               // 8 MB bf16 V^T

    float* ctx_out  = (float*)d_out;
    float* attn_out = ctx_out + (size_t)2 * 2048 * 1024;

    dim3 g1(8, 32, 3);
    qkv_proj<<<g1, 256, 0, stream>>>(query, key_, value, Wq, bq, Wk, bk, Wv, bv,
                                     q_ws, kb_ws, vt_ws);
    attn_fused<<<512, 256, 0, stream>>>(q_ws, kb_ws, vt_ws, ctx_out, attn_out);
}

// Round 3
// 313.755 us; speedup vs baseline: 1.4292x; 1.3060x over previous
//
#include <hip/hip_runtime.h>

// MultiHeadAttention: B=2,S=2048,D=1024,H=16,Dh=64, fp32 in/out.
// K1: QKV projection (split-bf16 MFMA, fp32-accurate), reg-prefetch pipeline.
//     Q -> ws fp32 [4096][1024] (pre-scaled by (1/8)*log2e for exp2 softmax);
//     K -> ws bf16 [4096][1024]; V -> ws bf16 TRANSPOSED [1024][4096].
// K2: per (b,h,q-block128), XCD-swizzled. KV tiles of 64 rows, double-buffered
//     async global_load_lds, ONE barrier per tile (T3 2-phase pipeline).
//     passA: row sums L (q_hi-only scores, lane-partial, reduce once).
//     passB: attn write (vectorized via P-LDS readback) + PV accumulate.
// ws: 16MB (Q fp32) + 8MB (K bf16) + 8MB (Vt bf16) = 32MB.

typedef __attribute__((ext_vector_type(8))) short bf16x8;
typedef __attribute__((ext_vector_type(4))) float f32x4;

#define MFMA16(a, b, c) __builtin_amdgcn_mfma_f32_16x16x32_bf16((a), (b), (c), 0, 0, 0)

static __device__ __forceinline__ unsigned short f2bf(float x) {
    unsigned int u = __builtin_bit_cast(unsigned int, x);
    u += 0x7fffu + ((u >> 16) & 1u);           // round-to-nearest-even
    return (unsigned short)(u >> 16);
}
static __device__ __forceinline__ float bf2f(unsigned short s) {
    return __builtin_bit_cast(float, ((unsigned int)s) << 16);
}
// split fp32 -> bf16 hi + bf16 lo (x ~= hi + lo to ~2^-17 rel)
static __device__ __forceinline__ void split8(float4 f0, float4 f1, bf16x8& vh, bf16x8& vl) {
    float a; unsigned short hb;
    a = f0.x; hb = f2bf(a); vh[0] = (short)hb; vl[0] = (short)f2bf(a - bf2f(hb));
    a = f0.y; hb = f2bf(a); vh[1] = (short)hb; vl[1] = (short)f2bf(a - bf2f(hb));
    a = f0.z; hb = f2bf(a); vh[2] = (short)hb; vl[2] = (short)f2bf(a - bf2f(hb));
    a = f0.w; hb = f2bf(a); vh[3] = (short)hb; vl[3] = (short)f2bf(a - bf2f(hb));
    a = f1.x; hb = f2bf(a); vh[4] = (short)hb; vl[4] = (short)f2bf(a - bf2f(hb));
    a = f1.y; hb = f2bf(a); vh[5] = (short)hb; vl[5] = (short)f2bf(a - bf2f(hb));
    a = f1.z; hb = f2bf(a); vh[6] = (short)hb; vl[6] = (short)f2bf(a - bf2f(hb));
    a = f1.w; hb = f2bf(a); vh[7] = (short)hb; vl[7] = (short)f2bf(a - bf2f(hb));
}

// async global(bf16,16B) -> LDS, dest = wave-uniform base + lane*16
static __device__ __forceinline__ void gload16(const unsigned short* g, unsigned short* l) {
    __builtin_amdgcn_global_load_lds(
        (const __attribute__((address_space(1))) unsigned int*)g,
        (__attribute__((address_space(3))) unsigned int*)l, 16, 0, 0);
}

// ---------------- K1: QKV projection GEMM  C[m,n] = sum_k X[m,k]*W[n,k] + b[n]
__global__ __launch_bounds__(256, 2) void qkv_proj(
    const float* __restrict__ query, const float* __restrict__ key_, const float* __restrict__ value,
    const float* __restrict__ Wq, const float* __restrict__ bq,
    const float* __restrict__ Wk, const float* __restrict__ bk,
    const float* __restrict__ Wv, const float* __restrict__ bv,
    float* __restrict__ q_ws, unsigned short* __restrict__ kb_ws, unsigned short* __restrict__ vt_ws)
{
    __shared__ unsigned short sAh[128 * 40];   // +8 pad: conflict-free b128 frag reads
    __shared__ unsigned short sAl[128 * 40];
    __shared__ unsigned short sBh[128 * 40];
    __shared__ unsigned short sBl[128 * 40];

    const int z = blockIdx.z;
    const float* __restrict__ X    = (z == 0) ? query : (z == 1) ? key_ : value;
    const float* __restrict__ W    = (z == 0) ? Wq    : (z == 1) ? Wk   : Wv;
    const float* __restrict__ bias = (z == 0) ? bq    : (z == 1) ? bk   : bv;

    const int t = threadIdx.x;
    const int l = t & 63;
    const int w = t >> 6;
    const int lr = l & 15;
    const int lk = (l >> 4) * 8;
    const int m0 = blockIdx.y * 128;
    const int n0 = blockIdx.x * 128;
    const int wr = (w >> 1) * 64;
    const int wc = (w & 1) * 64;
    const int srow = t >> 1;            // staging: 2 threads per 128-row, 16 floats each
    const int sc0 = (t & 1) * 16;

    f32x4 acc[4][4];
#pragma unroll
    for (int i = 0; i < 4; i++)
#pragma unroll
        for (int j = 0; j < 4; j++) acc[i][j] = (f32x4){0.f, 0.f, 0.f, 0.f};

    float4 fa[4], fb[4];
#pragma unroll
    for (int u = 0; u < 4; u++) {       // prologue: prefetch K-step 0
        fa[u] = *(const float4*)(&X[(size_t)(m0 + srow) * 1024 + sc0 + 4 * u]);
        fb[u] = *(const float4*)(&W[(size_t)(n0 + srow) * 1024 + sc0 + 4 * u]);
    }

    for (int kk = 0; kk < 1024; kk += 32) {
        __syncthreads();                // prev tile reads done
#pragma unroll
        for (int u = 0; u < 4; u++) {   // convert + LDS write from regs
            ushort4 ah, al, bh, bl;
            ah.x = f2bf(fa[u].x); al.x = f2bf(fa[u].x - bf2f(ah.x));
            ah.y = f2bf(fa[u].y); al.y = f2bf(fa[u].y - bf2f(ah.y));
            ah.z = f2bf(fa[u].z); al.z = f2bf(fa[u].z - bf2f(ah.z));
            ah.w = f2bf(fa[u].w); al.w = f2bf(fa[u].w - bf2f(ah.w));
            bh.x = f2bf(fb[u].x); bl.x = f2bf(fb[u].x - bf2f(bh.x));
            bh.y = f2bf(fb[u].y); bl.y = f2bf(fb[u].y - bf2f(bh.y));
            bh.z = f2bf(fb[u].z); bl.z = f2bf(fb[u].z - bf2f(bh.z));
            bh.w = f2bf(fb[u].w); bl.w = f2bf(fb[u].w - bf2f(bh.w));
            const int si = srow * 40 + sc0 + 4 * u;
            *(ushort4*)(&sAh[si]) = ah;
            *(ushort4*)(&sAl[si]) = al;
            *(ushort4*)(&sBh[si]) = bh;
            *(ushort4*)(&sBl[si]) = bl;
        }
        __syncthreads();                // writes visible
        if (kk + 32 < 1024) {
#pragma unroll
            for (int u = 0; u < 4; u++) {   // issue next loads: latency hides under MFMA
                fa[u] = *(const float4*)(&X[(size_t)(m0 + srow) * 1024 + kk + 32 + sc0 + 4 * u]);
                fb[u] = *(const float4*)(&W[(size_t)(n0 + srow) * 1024 + kk + 32 + sc0 + 4 * u]);
            }
        }
        bf16x8 Ah[4], Al[4], Bh[4], Bl[4];
#pragma unroll
        for (int i = 0; i < 4; i++) {
            Ah[i] = *(const bf16x8*)(&sAh[(wr + i * 16 + lr) * 40 + lk]);
            Al[i] = *(const bf16x8*)(&sAl[(wr + i * 16 + lr) * 40 + lk]);
            Bh[i] = *(const bf16x8*)(&sBh[(wc + i * 16 + lr) * 40 + lk]);
            Bl[i] = *(const bf16x8*)(&sBl[(wc + i * 16 + lr) * 40 + lk]);
        }
        __builtin_amdgcn_s_setprio(1);
#pragma unroll
        for (int i = 0; i < 4; i++)
#pragma unroll
            for (int j = 0; j < 4; j++) {
                acc[i][j] = MFMA16(Ah[i], Bh[j], acc[i][j]);
                acc[i][j] = MFMA16(Ah[i], Bl[j], acc[i][j]);
                acc[i][j] = MFMA16(Al[i], Bh[j], acc[i][j]);
            }
        __builtin_amdgcn_s_setprio(0);
    }

    // epilogue: C/D layout col=lane&15, row=(lane>>4)*4+r
#pragma unroll
    for (int i = 0; i < 4; i++)
#pragma unroll
        for (int j = 0; j < 4; j++) {
            const int gcol = n0 + wc + j * 16 + lr;
            const float bb = bias[gcol];
            const int grow0 = m0 + wr + i * 16 + (l >> 4) * 4;
            if (z == 2) {  // V: bf16, transposed [1024][4096]
                ushort4 pk;
                pk.x = f2bf(acc[i][j][0] + bb);
                pk.y = f2bf(acc[i][j][1] + bb);
                pk.z = f2bf(acc[i][j][2] + bb);
                pk.w = f2bf(acc[i][j][3] + bb);
                *(ushort4*)(&vt_ws[(size_t)gcol * 4096 + grow0]) = pk;
            } else if (z == 1) {  // K: bf16 row-major
#pragma unroll
                for (int r = 0; r < 4; r++)
                    kb_ws[(size_t)(grow0 + r) * 1024 + gcol] = f2bf(acc[i][j][r] + bb);
            } else {             // Q: fp32, (1/sqrt(Dh))*log2e folded in (exp2 softmax)
#pragma unroll
                for (int r = 0; r < 4; r++)
                    q_ws[(size_t)(grow0 + r) * 1024 + gcol] =
                        (acc[i][j][r] + bb) * 0.1803368801111244f;
            }
        }
}

// ---------------- K2 helpers: 64-row KV tile staging (async, swizzled source)
static __device__ __forceinline__ void stageK64(
    const unsigned short* __restrict__ kb_ws, unsigned short* dst,
    int b, int h, int k0, int w, int l)
{
#pragma unroll
    for (int u = 0; u < 2; u++) {
        const int row = w * 16 + u * 8 + (l >> 3);
        const int col = ((l & 7) * 8) ^ ((row & 7) << 3);
        gload16(&kb_ws[(size_t)(b * 2048 + k0 + row) * 1024 + h * 64 + col],
                &dst[w * 1024 + u * 512]);
    }
}
static __device__ __forceinline__ void stageV64(
    const unsigned short* __restrict__ vt_ws, unsigned short* dst,
    int b, int h, int k0, int w, int l)
{
#pragma unroll
    for (int u = 0; u < 2; u++) {
        const int d = w * 16 + u * 8 + (l >> 3);
        const int kk = ((l & 7) * 8) ^ ((d & 7) << 3);
        gload16(&vt_ws[(size_t)(h * 64 + d) * 4096 + b * 2048 + k0 + kk],
                &dst[w * 1024 + u * 512]);
    }
}

// QK^T scores on one 64-row K tile: A = Q frag (hi [, lo]), B = K rows from LDS
template<int TERMS>
static __device__ __forceinline__ void scores64(
    const unsigned short* sK,
    const bf16x8 (&qh)[2][2], const bf16x8 (&ql)[2][2],
    int lr, int lg, f32x4 (&sc)[2][4])
{
#pragma unroll
    for (int m = 0; m < 2; m++)
#pragma unroll
        for (int n = 0; n < 4; n++) sc[m][n] = (f32x4){0.f, 0.f, 0.f, 0.f};
    __builtin_amdgcn_s_setprio(1);
#pragma unroll
    for (int n = 0; n < 4; n++) {
        const int row = n * 16 + lr;
#pragma unroll
        for (int kc = 0; kc < 2; kc++) {
            const int idx = (row * 64 + kc * 32 + lg * 8) ^ ((row & 7) << 3);
            const bf16x8 Bh = *(const bf16x8*)(&sK[idx]);
#pragma unroll
            for (int m = 0; m < 2; m++) {
                sc[m][n] = MFMA16(qh[m][kc], Bh, sc[m][n]);
                if (TERMS == 2) sc[m][n] = MFMA16(ql[m][kc], Bh, sc[m][n]);
            }
        }
    }
    __builtin_amdgcn_s_setprio(0);
}

// ---------------- K2: fused attention per (b, h, q-block of 128)
__global__ __launch_bounds__(256, 2) void attn_fused(
    const float* __restrict__ q_ws, const unsigned short* __restrict__ kb_ws,
    const unsigned short* __restrict__ vt_ws,
    float* __restrict__ ctx_out, float* __restrict__ attn_out)
{
    __shared__ unsigned short sK[2][64 * 64];  // 2x8KB K tile (bf16, XOR-swizzled)
    __shared__ unsigned short sV[2][64 * 64];  // 2x8KB V^T tile [d][k]
    __shared__ unsigned short sP[128 * 64];    // 16KB P' tile, per-wave rows
    __shared__ float sInvL[128];

    const int t = threadIdx.x;
    const int l = t & 63;
    const int w = t >> 6;
    const int lr = l & 15;
    const int lg = l >> 4;
    // XCD swizzle: 512 blocks = 8 XCDs x 64; chunk shares 4 (b,h) K/V panels (L2-fit)
    const int o  = (blockIdx.x & 7) * 64 + (blockIdx.x >> 3);
    const int qb = o & 15;
    const int h  = (o >> 4) & 15;
    const int b  = o >> 8;
    const int sq0 = qb * 128 + w * 32;   // this wave's 32 q-rows

    // Q fragments (hi/lo), fp32 source, one-time
    bf16x8 qh[2][2], ql[2][2];
#pragma unroll
    for (int m = 0; m < 2; m++) {
        const int grow = b * 2048 + sq0 + m * 16 + lr;
#pragma unroll
        for (int kc = 0; kc < 2; kc++) {
            const float* src = &q_ws[(size_t)grow * 1024 + h * 64 + kc * 32 + lg * 8];
            float4 f0 = *(const float4*)(src);
            float4 f1 = *(const float4*)(src + 4);
            split8(f0, f1, qh[m][kc], ql[m][kc]);
        }
    }

    // ---- pass A: lane-partial row sums of exp2(s); reduce across lr once at end
    float La[2][4];
#pragma unroll
    for (int m = 0; m < 2; m++)
#pragma unroll
        for (int r = 0; r < 4; r++) La[m][r] = 0.f;

    stageK64(kb_ws, sK[0], b, h, 0, w, l);
    __syncthreads();
    for (int kt = 0; kt < 32; kt++) {
        const int cur = kt & 1;
        if (kt < 31) stageK64(kb_ws, sK[cur ^ 1], b, h, (kt + 1) * 64, w, l);
        f32x4 sc[2][4];
        scores64<1>(sK[cur], qh, ql, lr, lg, sc);
#pragma unroll
        for (int m = 0; m < 2; m++)
#pragma unroll
            for (int r = 0; r < 4; r++)
                La[m][r] += exp2f(sc[m][0][r]) + exp2f(sc[m][1][r]) +
                            exp2f(sc[m][2][r]) + exp2f(sc[m][3][r]);
        __syncthreads();
    }

    float invL[2][4];
#pragma unroll
    for (int m = 0; m < 2; m++)
#pragma unroll
        for (int r = 0; r < 4; r++) {
            float v = La[m][r];
            v += __shfl_xor(v, 1);
            v += __shfl_xor(v, 2);
            v += __shfl_xor(v, 4);
            v += __shfl_xor(v, 8);
            invL[m][r] = 1.0f / v;
            if (lr == 0) sInvL[w * 32 + m * 16 + lg * 4 + r] = invL[m][r];
        }

    // ---- pass B: attn write + PV accumulate (pipelined K+V staging)
    f32x4 pv[2][4];
#pragma unroll
    for (int m = 0; m < 2; m++)
#pragma unroll
        for (int n = 0; n < 4; n++) pv[m][n] = (f32x4){0.f, 0.f, 0.f, 0.f};

    stageK64(kb_ws, sK[0], b, h, 0, w, l);
    stageV64(vt_ws, sV[0], b, h, 0, w, l);
    __syncthreads();                    // also publishes sInvL
    for (int kt = 0; kt < 32; kt++) {
        const int cur = kt & 1;
        const int k0 = kt * 64;
        if (kt < 31) {
            stageK64(kb_ws, sK[cur ^ 1], b, h, k0 + 64, w, l);
            stageV64(vt_ws, sV[cur ^ 1], b, h, k0 + 64, w, l);
        }
        f32x4 sc[2][4];
        scores64<2>(sK[cur], qh, ql, lr, lg, sc);

        // exp2 -> P' bf16 into wave-private sP rows
#pragma unroll
        for (int m = 0; m < 2; m++)
#pragma unroll
            for (int r = 0; r < 4; r++) {
                const int prow = w * 32 + m * 16 + lg * 4 + r;
#pragma unroll
                for (int n = 0; n < 4; n++) {
                    const float p = exp2f(sc[m][n][r]);
                    sP[(prow * 64 + n * 16 + lr) ^ ((prow & 7) << 3)] = f2bf(p);
                }
            }
        // attn store: vectorized readback, float4 per lane
#pragma unroll
        for (int i = 0; i < 8; i++) {
            const int prow = w * 32 + lg * 8 + i;
            const float il = sInvL[prow];
            ushort4 pk = *(const ushort4*)(&sP[(prow * 64 + lr * 4) ^ ((prow & 7) << 3)]);
            float4 oo;
            oo.x = bf2f(pk.x) * il;
            oo.y = bf2f(pk.y) * il;
            oo.z = bf2f(pk.z) * il;
            oo.w = bf2f(pk.w) * il;
            const size_t arow = (size_t)(h * 2 + b) * 2048 + qb * 128 + prow;
            *(float4*)(&attn_out[arow * 2048 + k0 + lr * 4]) = oo;
        }
        // PV: ctx += P' @ V over this 64-k tile
        __builtin_amdgcn_s_setprio(1);
#pragma unroll
        for (int kcl = 0; kcl < 2; kcl++) {
            bf16x8 pa[2];
#pragma unroll
            for (int m = 0; m < 2; m++) {
                const int prow = w * 32 + m * 16 + lr;
                pa[m] = *(const bf16x8*)(&sP[(prow * 64 + kcl * 32 + lg * 8) ^ ((prow & 7) << 3)]);
            }
#pragma unroll
            for (int n = 0; n < 4; n++) {
                const int vrow = n * 16 + lr;
                const bf16x8 vb = *(const bf16x8*)(&sV[cur][(vrow * 64 + kcl * 32 + lg * 8) ^ ((vrow & 7) << 3)]);
#pragma unroll
                for (int m = 0; m < 2; m++) pv[m][n] = MFMA16(pa[m], vb, pv[m][n]);
            }
        }
        __builtin_amdgcn_s_setprio(0);
        __syncthreads();                // one barrier/tile: drains prefetch after compute
    }

    // epilogue: context = (P' @ V) / L
#pragma unroll
    for (int m = 0; m < 2; m++)
#pragma unroll
        for (int r = 0; r < 4; r++) {
            const int sq = sq0 + m * 16 + lg * 4 + r;
            const float il = invL[m][r];
#pragma unroll
            for (int n = 0; n < 4; n++)
                ctx_out[((size_t)(b * 2048 + sq)) * 1024 + h * 64 + n * 16 + lr] =
                    pv[m][n][r] * il;
        }
}

extern "C" void kernel_launch(void* const* d_in, const int* in_sizes, int n_in,
                              void* d_out, int out_size, void* d_ws, size_t ws_size,
                              hipStream_t stream)
{
    const float* query = (const float*)d_in[0];
    const float* key_  = (const float*)d_in[1];
    const float* value = (const float*)d_in[2];
    const float* Wq = (const float*)d_in[3];
    const float* bq = (const float*)d_in[4];
    const float* Wk = (const float*)d_in[5];
    const float* bk = (const float*)d_in[6];
    const float* Wv = (const float*)d_in[7];
    const float* bv = (const float*)d_in[8];

    float* q_ws = (float*)d_ws;                                        // 16 MB fp32
    unsigned short* kb_ws = (unsigned short*)(q_ws + (size_t)4096 * 1024);  // 8 MB bf16
    unsigned short* vt_ws = kb_ws + (size_t)4096 * 1024;               // 8 MB bf16 V^T

    float* ctx_out  = (float*)d_out;
    float* attn_out = ctx_out + (size_t)2 * 2048 * 1024;

    dim3 g1(8, 32, 3);
    qkv_proj<<<g1, 256, 0, stream>>>(query, key_, value, Wq, bq, Wk, bk, Wv, bv,
                                     q_ws, kb_ws, vt_ws);
    attn_fused<<<512, 256, 0, stream>>>(q_ws, kb_ws, vt_ws, ctx_out, attn_out);
}

// Round 4
// 275.855 us; speedup vs baseline: 1.6255x; 1.1374x over previous
//
#include <hip/hip_runtime.h>

// MultiHeadAttention: B=2,S=2048,D=1024,H=16,Dh=64, fp32 in/out.
// All-bf16 single-term MFMA (error budget: score err ~3e-3 damped by sqrt(sum p^2)
// ~0.1 at outputs; measured headroom 3.4x at R3).
// K1: QKV projection, reg-prefetch pipeline. Q -> bf16 [4096][1024] pre-scaled
//     (1/8)*log2e; K -> bf16 [4096][1024]; V -> bf16 TRANSPOSED [1024][4096].
// K2: per (b,h,q-block128), XCD-swizzled.
//     passA: L row-sums; 256-row K windows (4 sub-tiles/barrier), dbuf, 8 barriers.
//     passB: 64-row K+V tiles, dbuf, attn write via sP readback + PV accumulate.
// ws: 8+8+8 = 24MB.

typedef __attribute__((ext_vector_type(8))) short bf16x8;
typedef __attribute__((ext_vector_type(4))) float f32x4;

#define MFMA16(a, b, c) __builtin_amdgcn_mfma_f32_16x16x32_bf16((a), (b), (c), 0, 0, 0)

static __device__ __forceinline__ unsigned short f2bf(float x) {
    unsigned int u = __builtin_bit_cast(unsigned int, x);
    u += 0x7fffu + ((u >> 16) & 1u);           // round-to-nearest-even
    return (unsigned short)(u >> 16);
}
static __device__ __forceinline__ float bf2f(unsigned short s) {
    return __builtin_bit_cast(float, ((unsigned int)s) << 16);
}

// async global(bf16,16B) -> LDS, dest = wave-uniform base + lane*16
static __device__ __forceinline__ void gload16(const unsigned short* g, unsigned short* l) {
    __builtin_amdgcn_global_load_lds(
        (const __attribute__((address_space(1))) unsigned int*)g,
        (__attribute__((address_space(3))) unsigned int*)l, 16, 0, 0);
}

// ---------------- K1: QKV projection GEMM  C[m,n] = sum_k X[m,k]*W[n,k] + b[n]
__global__ __launch_bounds__(256, 3) void qkv_proj(
    const float* __restrict__ query, const float* __restrict__ key_, const float* __restrict__ value,
    const float* __restrict__ Wq, const float* __restrict__ bq,
    const float* __restrict__ Wk, const float* __restrict__ bk,
    const float* __restrict__ Wv, const float* __restrict__ bv,
    unsigned short* __restrict__ qb_ws, unsigned short* __restrict__ kb_ws,
    unsigned short* __restrict__ vt_ws)
{
    __shared__ unsigned short sA[128 * 40];   // +8 pad: conflict-free b128 frag reads
    __shared__ unsigned short sB[128 * 40];

    const int z = blockIdx.z;
    const float* __restrict__ X    = (z == 0) ? query : (z == 1) ? key_ : value;
    const float* __restrict__ W    = (z == 0) ? Wq    : (z == 1) ? Wk   : Wv;
    const float* __restrict__ bias = (z == 0) ? bq    : (z == 1) ? bk   : bv;

    const int t = threadIdx.x;
    const int l = t & 63;
    const int w = t >> 6;
    const int lr = l & 15;
    const int lk = (l >> 4) * 8;
    const int m0 = blockIdx.y * 128;
    const int n0 = blockIdx.x * 128;
    const int wr = (w >> 1) * 64;
    const int wc = (w & 1) * 64;
    const int srow = t >> 1;            // staging: 2 threads per 128-row, 16 floats each
    const int sc0 = (t & 1) * 16;

    f32x4 acc[4][4];
#pragma unroll
    for (int i = 0; i < 4; i++)
#pragma unroll
        for (int j = 0; j < 4; j++) acc[i][j] = (f32x4){0.f, 0.f, 0.f, 0.f};

    float4 fa[4], fb[4];
#pragma unroll
    for (int u = 0; u < 4; u++) {       // prologue: prefetch K-step 0
        fa[u] = *(const float4*)(&X[(size_t)(m0 + srow) * 1024 + sc0 + 4 * u]);
        fb[u] = *(const float4*)(&W[(size_t)(n0 + srow) * 1024 + sc0 + 4 * u]);
    }

    for (int kk = 0; kk < 1024; kk += 32) {
        __syncthreads();                // prev tile reads done
#pragma unroll
        for (int u = 0; u < 4; u++) {   // convert + LDS write from regs
            ushort4 ah, bh;
            ah.x = f2bf(fa[u].x); ah.y = f2bf(fa[u].y);
            ah.z = f2bf(fa[u].z); ah.w = f2bf(fa[u].w);
            bh.x = f2bf(fb[u].x); bh.y = f2bf(fb[u].y);
            bh.z = f2bf(fb[u].z); bh.w = f2bf(fb[u].w);
            const int si = srow * 40 + sc0 + 4 * u;
            *(ushort4*)(&sA[si]) = ah;
            *(ushort4*)(&sB[si]) = bh;
        }
        __syncthreads();                // writes visible
        if (kk + 32 < 1024) {
#pragma unroll
            for (int u = 0; u < 4; u++) {   // issue next loads: latency hides under MFMA
                fa[u] = *(const float4*)(&X[(size_t)(m0 + srow) * 1024 + kk + 32 + sc0 + 4 * u]);
                fb[u] = *(const float4*)(&W[(size_t)(n0 + srow) * 1024 + kk + 32 + sc0 + 4 * u]);
            }
        }
        bf16x8 Ah[4], Bh[4];
#pragma unroll
        for (int i = 0; i < 4; i++) {
            Ah[i] = *(const bf16x8*)(&sA[(wr + i * 16 + lr) * 40 + lk]);
            Bh[i] = *(const bf16x8*)(&sB[(wc + i * 16 + lr) * 40 + lk]);
        }
        __builtin_amdgcn_s_setprio(1);
#pragma unroll
        for (int i = 0; i < 4; i++)
#pragma unroll
            for (int j = 0; j < 4; j++)
                acc[i][j] = MFMA16(Ah[i], Bh[j], acc[i][j]);
        __builtin_amdgcn_s_setprio(0);
    }

    // epilogue: C/D layout col=lane&15, row=(lane>>4)*4+r
#pragma unroll
    for (int i = 0; i < 4; i++)
#pragma unroll
        for (int j = 0; j < 4; j++) {
            const int gcol = n0 + wc + j * 16 + lr;
            const float bb = bias[gcol];
            const int grow0 = m0 + wr + i * 16 + (l >> 4) * 4;
            if (z == 2) {  // V: bf16, transposed [1024][4096]
                ushort4 pk;
                pk.x = f2bf(acc[i][j][0] + bb);
                pk.y = f2bf(acc[i][j][1] + bb);
                pk.z = f2bf(acc[i][j][2] + bb);
                pk.w = f2bf(acc[i][j][3] + bb);
                *(ushort4*)(&vt_ws[(size_t)gcol * 4096 + grow0]) = pk;
            } else if (z == 1) {  // K: bf16 row-major
#pragma unroll
                for (int r = 0; r < 4; r++)
                    kb_ws[(size_t)(grow0 + r) * 1024 + gcol] = f2bf(acc[i][j][r] + bb);
            } else {             // Q: bf16, (1/sqrt(Dh))*log2e folded in (exp2 softmax)
#pragma unroll
                for (int r = 0; r < 4; r++)
                    qb_ws[(size_t)(grow0 + r) * 1024 + gcol] =
                        f2bf((acc[i][j][r] + bb) * 0.1803368801111244f);
            }
        }
}

// ---------------- K2 staging helpers (async, swizzled source)
// stage 64 rows (this wave's share is rows [w*16, w*16+16) of a 64-row tile)
static __device__ __forceinline__ void stageK64(
    const unsigned short* __restrict__ kb_ws, unsigned short* dst,
    int b, int h, int k0, int w, int l)
{
#pragma unroll
    for (int u = 0; u < 2; u++) {
        const int row = w * 16 + u * 8 + (l >> 3);
        const int col = ((l & 7) * 8) ^ ((row & 7) << 3);
        gload16(&kb_ws[(size_t)(b * 2048 + k0 + row) * 1024 + h * 64 + col],
                &dst[w * 1024 + u * 512]);
    }
}
static __device__ __forceinline__ void stageV64(
    const unsigned short* __restrict__ vt_ws, unsigned short* dst,
    int b, int h, int k0, int w, int l)
{
#pragma unroll
    for (int u = 0; u < 2; u++) {
        const int d = w * 16 + u * 8 + (l >> 3);
        const int kk = ((l & 7) * 8) ^ ((d & 7) << 3);
        gload16(&vt_ws[(size_t)(h * 64 + d) * 4096 + b * 2048 + k0 + kk],
                &dst[w * 1024 + u * 512]);
    }
}
// pass A: stage a 256-row window; wave w owns rows [w*64, w*64+64)
static __device__ __forceinline__ void stageWin256(
    const unsigned short* __restrict__ kb_ws, unsigned short* dst,
    int b, int h, int k0, int w, int l)
{
#pragma unroll
    for (int u = 0; u < 8; u++) {
        const int row = w * 64 + u * 8 + (l >> 3);
        const int col = ((l & 7) * 8) ^ ((row & 7) << 3);
        gload16(&kb_ws[(size_t)(b * 2048 + k0 + row) * 1024 + h * 64 + col],
                &dst[w * 4096 + u * 512]);
    }
}

// QK^T scores on one 64-row K tile (bf16 single-term)
static __device__ __forceinline__ void scores64(
    const unsigned short* sK, const bf16x8 (&qf)[2][2],
    int lr, int lg, f32x4 (&sc)[2][4])
{
#pragma unroll
    for (int m = 0; m < 2; m++)
#pragma unroll
        for (int n = 0; n < 4; n++) sc[m][n] = (f32x4){0.f, 0.f, 0.f, 0.f};
    __builtin_amdgcn_s_setprio(1);
#pragma unroll
    for (int n = 0; n < 4; n++) {
        const int row = n * 16 + lr;
#pragma unroll
        for (int kc = 0; kc < 2; kc++) {
            const int idx = (row * 64 + kc * 32 + lg * 8) ^ ((row & 7) << 3);
            const bf16x8 Bh = *(const bf16x8*)(&sK[idx]);
#pragma unroll
            for (int m = 0; m < 2; m++)
                sc[m][n] = MFMA16(qf[m][kc], Bh, sc[m][n]);
        }
    }
    __builtin_amdgcn_s_setprio(0);
}

// ---------------- K2: fused attention per (b, h, q-block of 128)
__global__ __launch_bounds__(256, 2) void attn_fused(
    const unsigned short* __restrict__ qb_ws, const unsigned short* __restrict__ kb_ws,
    const unsigned short* __restrict__ vt_ws,
    float* __restrict__ ctx_out, float* __restrict__ attn_out)
{
    // 64KB union region (ushort idx):
    //   passA: kwin[2][256*64]   at 0 and 16384
    //   passB: sK2[2][64*64] at 0,4096 ; sV2[2][64*64] at 8192,12288 ; sP[128*64] at 16384
    __shared__ unsigned short smem[32768];
    __shared__ float sInvL[128];
    unsigned short* const kwin0 = smem;
    unsigned short* const kwin1 = smem + 16384;
    unsigned short* const sK2   = smem;          // [2][4096]
    unsigned short* const sV2   = smem + 8192;   // [2][4096]
    unsigned short* const sP    = smem + 16384;  // [128*64]

    const int t = threadIdx.x;
    const int l = t & 63;
    const int w = t >> 6;
    const int lr = l & 15;
    const int lg = l >> 4;
    // XCD swizzle: 512 blocks = 8 XCDs x 64; chunk shares 4 (b,h) K/V panels (L2-fit)
    const int o  = (blockIdx.x & 7) * 64 + (blockIdx.x >> 3);
    const int qb = o & 15;
    const int h  = (o >> 4) & 15;
    const int b  = o >> 8;
    const int sq0 = qb * 128 + w * 32;   // this wave's 32 q-rows

    // Q fragments, bf16 direct (scale+log2e already folded by K1)
    bf16x8 qf[2][2];
#pragma unroll
    for (int m = 0; m < 2; m++) {
        const int grow = b * 2048 + sq0 + m * 16 + lr;
#pragma unroll
        for (int kc = 0; kc < 2; kc++)
            qf[m][kc] = *(const bf16x8*)(&qb_ws[(size_t)grow * 1024 + h * 64 + kc * 32 + lg * 8]);
    }

    // ---- pass A: lane-partial row sums of exp2(s); 256-row windows, dbuf
    float La[2][4];
#pragma unroll
    for (int m = 0; m < 2; m++)
#pragma unroll
        for (int r = 0; r < 4; r++) La[m][r] = 0.f;

    stageWin256(kb_ws, kwin0, b, h, 0, w, l);
    __syncthreads();
    for (int kt = 0; kt < 8; kt++) {
        unsigned short* cur = (kt & 1) ? kwin1 : kwin0;
        unsigned short* nxt = (kt & 1) ? kwin0 : kwin1;
        if (kt < 7) stageWin256(kb_ws, nxt, b, h, (kt + 1) * 256, w, l);
#pragma unroll
        for (int sub = 0; sub < 4; sub++) {
            f32x4 sc[2][4];
            scores64(&cur[sub * 4096], qf, lr, lg, sc);
#pragma unroll
            for (int m = 0; m < 2; m++)
#pragma unroll
                for (int r = 0; r < 4; r++)
                    La[m][r] += exp2f(sc[m][0][r]) + exp2f(sc[m][1][r]) +
                                exp2f(sc[m][2][r]) + exp2f(sc[m][3][r]);
        }
        __syncthreads();                // drains prefetch; protects buffer reuse
    }

    float invL[2][4];
#pragma unroll
    for (int m = 0; m < 2; m++)
#pragma unroll
        for (int r = 0; r < 4; r++) {
            float v = La[m][r];
            v += __shfl_xor(v, 1);
            v += __shfl_xor(v, 2);
            v += __shfl_xor(v, 4);
            v += __shfl_xor(v, 8);
            invL[m][r] = 1.0f / v;
            if (lr == 0) sInvL[w * 32 + m * 16 + lg * 4 + r] = invL[m][r];
        }

    // ---- pass B: attn write + PV accumulate (64-row tiles, dbuf)
    f32x4 pv[2][4];
#pragma unroll
    for (int m = 0; m < 2; m++)
#pragma unroll
        for (int n = 0; n < 4; n++) pv[m][n] = (f32x4){0.f, 0.f, 0.f, 0.f};

    stageK64(kb_ws, sK2, b, h, 0, w, l);
    stageV64(vt_ws, sV2, b, h, 0, w, l);
    __syncthreads();                    // also publishes sInvL
    for (int kt = 0; kt < 32; kt++) {
        const int cur = (kt & 1) * 4096;
        const int nxt = 4096 - cur;
        const int k0 = kt * 64;
        if (kt < 31) {
            stageK64(kb_ws, sK2 + nxt, b, h, k0 + 64, w, l);
            stageV64(vt_ws, sV2 + nxt, b, h, k0 + 64, w, l);
        }
        f32x4 sc[2][4];
        scores64(sK2 + cur, qf, lr, lg, sc);

        // exp2 -> P' bf16 into wave-private sP rows
#pragma unroll
        for (int m = 0; m < 2; m++)
#pragma unroll
            for (int r = 0; r < 4; r++) {
                const int prow = w * 32 + m * 16 + lg * 4 + r;
#pragma unroll
                for (int n = 0; n < 4; n++) {
                    const float p = exp2f(sc[m][n][r]);
                    sP[(prow * 64 + n * 16 + lr) ^ ((prow & 7) << 3)] = f2bf(p);
                }
            }
        // attn store: vectorized readback, float4 per lane
#pragma unroll
        for (int i = 0; i < 8; i++) {
            const int prow = w * 32 + lg * 8 + i;
            const float il = sInvL[prow];
            ushort4 pk = *(const ushort4*)(&sP[(prow * 64 + lr * 4) ^ ((prow & 7) << 3)]);
            float4 oo;
            oo.x = bf2f(pk.x) * il;
            oo.y = bf2f(pk.y) * il;
            oo.z = bf2f(pk.z) * il;
            oo.w = bf2f(pk.w) * il;
            const size_t arow = (size_t)(h * 2 + b) * 2048 + qb * 128 + prow;
            *(float4*)(&attn_out[arow * 2048 + k0 + lr * 4]) = oo;
        }
        // PV: ctx += P' @ V over this 64-k tile
        __builtin_amdgcn_s_setprio(1);
#pragma unroll
        for (int kcl = 0; kcl < 2; kcl++) {
            bf16x8 pa[2];
#pragma unroll
            for (int m = 0; m < 2; m++) {
                const int prow = w * 32 + m * 16 + lr;
                pa[m] = *(const bf16x8*)(&sP[(prow * 64 + kcl * 32 + lg * 8) ^ ((prow & 7) << 3)]);
            }
#pragma unroll
            for (int n = 0; n < 4; n++) {
                const int vrow = n * 16 + lr;
                const bf16x8 vb = *(const bf16x8*)(&sV2[cur + ((vrow * 64 + kcl * 32 + lg * 8) ^ ((vrow & 7) << 3))]);
#pragma unroll
                for (int m = 0; m < 2; m++) pv[m][n] = MFMA16(pa[m], vb, pv[m][n]);
            }
        }
        __builtin_amdgcn_s_setprio(0);
        __syncthreads();                // one barrier/tile: drains prefetch after compute
    }

    // epilogue: context = (P' @ V) / L
#pragma unroll
    for (int m = 0; m < 2; m++)
#pragma unroll
        for (int r = 0; r < 4; r++) {
            const int sq = sq0 + m * 16 + lg * 4 + r;
            const float il = invL[m][r];
#pragma unroll
            for (int n = 0; n < 4; n++)
                ctx_out[((size_t)(b * 2048 + sq)) * 1024 + h * 64 + n * 16 + lr] =
                    pv[m][n][r] * il;
        }
}

extern "C" void kernel_launch(void* const* d_in, const int* in_sizes, int n_in,
                              void* d_out, int out_size, void* d_ws, size_t ws_size,
                              hipStream_t stream)
{
    const float* query = (const float*)d_in[0];
    const float* key_  = (const float*)d_in[1];
    const float* value = (const float*)d_in[2];
    const float* Wq = (const float*)d_in[3];
    const float* bq = (const float*)d_in[4];
    const float* Wk = (const float*)d_in[5];
    const float* bk = (const float*)d_in[6];
    const float* Wv = (const float*)d_in[7];
    const float* bv = (const float*)d_in[8];

    unsigned short* qb_ws = (unsigned short*)d_ws;                 // 8 MB bf16 (scaled)
    unsigned short* kb_ws = qb_ws + (size_t)4096 * 1024;           // 8 MB bf16
    unsigned short* vt_ws = kb_ws + (size_t)4096 * 1024;           // 8 MB bf16 V^T

    float* ctx_out  = (float*)d_out;
    float* attn_out = ctx_out + (size_t)2 * 2048 * 1024;

    dim3 g1(8, 32, 3);
    qkv_proj<<<g1, 256, 0, stream>>>(query, key_, value, Wq, bq, Wk, bk, Wv, bv,
                                     qb_ws, kb_ws, vt_ws);
    attn_fused<<<512, 256, 0, stream>>>(qb_ws, kb_ws, vt_ws, ctx_out, attn_out);
}